// Round 13
// baseline (111.577 us; speedup 1.0000x reference)
//
#include <hip/hip_runtime.h>
#include <hip/hip_fp16.h>

constexpr int N_NODES = 50000;
constexpr int N_EDGES = 400000;
constexpr int F = 128;

constexpr int NBUK2 = 4096;                      // key = (r>>13)<<9 | (c>>7)
constexpr int EPB   = 1024;                      // edges per hist/scatter block
constexpr int NBLK  = (N_EDGES + EPB - 1) / EPB; // 391
constexpr int NBLKP = 392;                       // padded stride [bucket][block]

typedef _Float16 f16x8 __attribute__((ext_vector_type(8)));
typedef _Float16 f16x4 __attribute__((ext_vector_type(4)));
typedef _Float16 f16x2 __attribute__((ext_vector_type(2)));
typedef float    f32x4 __attribute__((ext_vector_type(4)));

union v8v2 { f16x8 v8; f16x2 v2[4]; };

// XOR swizzle: flips half-index bits 3..5 by row&7 -> conflict-free frag reads.
__device__ __forceinline__ int swz(int row, int colh) {
    return (row * F + colh) ^ ((row & 7) << 3);
}

__device__ __forceinline__ unsigned ekey(unsigned r, unsigned c) {
    return ((r >> 13) << 9) | (c >> 7);          // 7 rgrp x 391 cblk
}

// =============== Algebra: score(e) = x_r^T M x_c + v.x_r + u.x_c + c0 =====
//   M = sum_h W_l^T W_a W_l (f16); u = sum_h W_l^T W_a^T b; v = sum_h W_l^T W_a b
//   c0 = sum_h b^T W_a b
__global__ __launch_bounds__(256) void gat_fuse(
    const float* __restrict__ W_lin, const float* __restrict__ b_lin,
    const float* __restrict__ W_att,
    _Float16* __restrict__ Mall, float* __restrict__ uvws)
{
    __shared__ float wlh[F * F];     // 64 KB
    __shared__ float wfs[F][8];
    __shared__ float bl[F];
    __shared__ float w12[2 * F];
    __shared__ float red[256];

    const int cb = blockIdx.x;
    const int t  = threadIdx.x;
    const int i  = t >> 1, j2 = (t & 1) * 4;
    const int ii = t & 127;

    float acc0 = 0, acc1 = 0, acc2 = 0, acc3 = 0;
    float puv = 0;
    float c0s = 0;

    for (int h = 0; h < 2; ++h) {
        __syncthreads();
        const float* WL = W_lin + h * F * F;
        const float* WA = W_att + h * F * F;
        #pragma unroll
        for (int q = 0; q < 16; ++q) {
            int idx = (q * 256 + t) * 4;
            *(float4*)(wlh + idx) = *(const float4*)(WL + idx);
        }
        if (t < F) bl[t] = b_lin[h * F + t];
        __syncthreads();

        {   int o = t >> 1, jb = (t & 1) * 4;
            float a0=0, a1=0, a2=0, a3=0;
            const float* war = WA + o * F;
            #pragma unroll 4
            for (int p = 0; p < F; ++p) {
                float wa = war[p];
                const float* wr = wlh + p * F + cb * 8 + jb;
                a0 += wa * wr[0]; a1 += wa * wr[1];
                a2 += wa * wr[2]; a3 += wa * wr[3];
            }
            wfs[o][jb+0]=a0; wfs[o][jb+1]=a1; wfs[o][jb+2]=a2; wfs[o][jb+3]=a3;
        }
        if (cb == 0) {
            if (t < F) {
                float s = 0;
                #pragma unroll 4
                for (int o = 0; o < F; ++o) s += WA[o * F + t] * bl[o];
                w12[t] = s;
            } else {
                int o = t - F;
                float s = 0;
                const float* war = WA + o * F;
                #pragma unroll 4
                for (int p = 0; p < F; ++p) s += war[p] * bl[p];
                w12[F + o] = s;
            }
        }
        __syncthreads();

        #pragma unroll 4
        for (int o = 0; o < F; ++o) {
            float wv = wlh[o * F + i];
            acc0 += wv * wfs[o][j2+0];
            acc1 += wv * wfs[o][j2+1];
            acc2 += wv * wfs[o][j2+2];
            acc3 += wv * wfs[o][j2+3];
        }
        if (cb == 0) {
            const float* wsrc = (t < F) ? w12 : (w12 + F);
            #pragma unroll 4
            for (int o = 0; o < F; ++o) puv += wlh[o * F + ii] * wsrc[o];
            red[t] = (t < F) ? bl[t] * w12[F + t] : 0.f;
            __syncthreads();
            #pragma unroll
            for (int d = 128; d > 0; d >>= 1) {
                if (t < d) red[t] += red[t + d];
                __syncthreads();
            }
            if (t == 0) c0s += red[0];
        }
    }

    f16x4 hv;
    hv[0]=(_Float16)acc0; hv[1]=(_Float16)acc1;
    hv[2]=(_Float16)acc2; hv[3]=(_Float16)acc3;
    *(f16x4*)(Mall + i * F + cb * 8 + j2) = hv;

    if (cb == 0) {
        uvws[(t < F ? 0 : F) + ii] = puv;
        if (t == 0) uvws[256] = c0s;
    }
}

// ------------- Deterministic 2-level counting sort by (r>>13, c>>7) -------
__global__ __launch_bounds__(256) void gat_hist(
    const int* __restrict__ ei, unsigned* __restrict__ bcnt)
{
    __shared__ unsigned h[NBUK2];
    const int t = threadIdx.x, b = blockIdx.x;
    #pragma unroll
    for (int i = 0; i < NBUK2 / 256; ++i) h[t + i * 256] = 0;
    __syncthreads();
    const int base = b * EPB;
    #pragma unroll
    for (int i = 0; i < EPB / 256; ++i) {
        int e = base + i * 256 + t;
        if (e < N_EDGES)
            atomicAdd(&h[ekey((unsigned)ei[e], (unsigned)ei[N_EDGES + e])], 1u);
    }
    __syncthreads();
    #pragma unroll
    for (int i = 0; i < NBUK2 / 256; ++i)
        bcnt[(t + i * 256) * NBLKP + b] = h[t + i * 256];
}

// one block per bucket: row-local exclusive prefix + bucket total
__global__ __launch_bounds__(512) void gat_scan_row(
    const unsigned* __restrict__ bcnt, unsigned* __restrict__ bof,
    unsigned* __restrict__ btot)
{
    __shared__ unsigned s[512];
    const int B = blockIdx.x, t = threadIdx.x;
    unsigned v = (t < NBLK) ? bcnt[B * NBLKP + t] : 0u;
    s[t] = v;
    __syncthreads();
    #pragma unroll
    for (int d = 1; d < 512; d <<= 1) {
        unsigned u = (t >= d) ? s[t - d] : 0u;
        __syncthreads();
        s[t] += u;
        __syncthreads();
    }
    if (t < NBLK) bof[B * NBLKP + t] = s[t] - v;
    if (t == 511) btot[B] = s[511];
}

// one block: exclusive scan over 4096 bucket totals (8/thread + LDS scan)
__global__ __launch_bounds__(512) void gat_scan_bkt(
    const unsigned* __restrict__ btot, unsigned* __restrict__ bbase)
{
    __shared__ unsigned s[512];
    const int t = threadIdx.x;
    unsigned loc[8];
    unsigned sum = 0;
    #pragma unroll
    for (int j = 0; j < 8; ++j) { loc[j] = btot[t * 8 + j]; sum += loc[j]; }
    s[t] = sum;
    __syncthreads();
    #pragma unroll
    for (int d = 1; d < 512; d <<= 1) {
        unsigned u = (t >= d) ? s[t - d] : 0u;
        __syncthreads();
        s[t] += u;
        __syncthreads();
    }
    unsigned run = s[t] - sum;
    #pragma unroll
    for (int j = 0; j < 8; ++j) { bbase[t * 8 + j] = run; run += loc[j]; }
}

__global__ __launch_bounds__(256) void gat_scatter(
    const int* __restrict__ ei, const unsigned* __restrict__ bof,
    const unsigned* __restrict__ bbase, uint2* __restrict__ sorted)
{
    __shared__ unsigned base[NBUK2];
    const int t = threadIdx.x, b = blockIdx.x;
    #pragma unroll
    for (int i = 0; i < NBUK2 / 256; ++i) {
        int B = t + i * 256;
        base[B] = bof[B * NBLKP + b] + bbase[B];
    }
    __syncthreads();
    const int bs = b * EPB;
    #pragma unroll
    for (int i = 0; i < EPB / 256; ++i) {
        int e = bs + i * 256 + t;
        if (e < N_EDGES) {
            unsigned r = (unsigned)ei[e], c = (unsigned)ei[N_EDGES + e];
            unsigned pos = atomicAdd(&base[ekey(r, c)], 1u);
            sorted[pos] = make_uint2(r | (c << 16), (unsigned)e);
        }
    }
}

// ---------------- GEMM: Z = x @ M^T, XH = f16(x), su/sv epilogue ----------
__global__ __launch_bounds__(256) void gat_gemm(
    const float* __restrict__ x,
    const _Float16* __restrict__ Mall,
    const float* __restrict__ uvws,
    _Float16* __restrict__ XH, _Float16* __restrict__ Z,
    float* __restrict__ su, float* __restrict__ sv)
{
    __shared__ _Float16 wbuf[F * F];
    __shared__ _Float16 stag[4][16 * F];

    const int t    = threadIdx.x;
    const int wave = t >> 6;
    const int lane = t & 63;
    const int r16  = lane & 15;
    const int kgrp = lane >> 4;
    const int node_base = blockIdx.x * 64 + wave * 16;

    #pragma unroll
    for (int i = 0; i < 8; ++i) {
        int idx8 = i * 256 + t;
        *(f16x8*)(wbuf + swz(idx8 >> 4, (idx8 & 15) * 8)) =
            *(const f16x8*)(Mall + (size_t)idx8 * 8);
    }

    f16x8 xf[4];
    {
        int xrow = node_base + r16;
        if (xrow >= N_NODES) xrow = N_NODES - 1;
        const float* xp = x + (size_t)xrow * F + kgrp * 8;
        #pragma unroll
        for (int kk = 0; kk < 4; ++kk) {
            float4 v0 = *(const float4*)(xp + kk * 32);
            float4 v1 = *(const float4*)(xp + kk * 32 + 4);
            f16x8 hv;
            hv[0]=(_Float16)v0.x; hv[1]=(_Float16)v0.y;
            hv[2]=(_Float16)v0.z; hv[3]=(_Float16)v0.w;
            hv[4]=(_Float16)v1.x; hv[5]=(_Float16)v1.y;
            hv[6]=(_Float16)v1.z; hv[7]=(_Float16)v1.w;
            xf[kk] = hv;
        }
    }
    __syncthreads();

    const int node = node_base + r16;

    #pragma unroll
    for (int c = 0; c < 8; ++c) {
        f16x8 aw[4];
        #pragma unroll
        for (int kk = 0; kk < 4; ++kk)
            aw[kk] = *(const f16x8*)(wbuf + swz(c * 16 + r16, kk * 32 + kgrp * 8));
        f32x4 acc = {0.f, 0.f, 0.f, 0.f};
        #pragma unroll
        for (int kk = 0; kk < 4; ++kk)
            acc = __builtin_amdgcn_mfma_f32_16x16x32_f16(aw[kk], xf[kk], acc, 0, 0, 0);
        f16x4 hv;
        hv[0]=(_Float16)acc[0]; hv[1]=(_Float16)acc[1];
        hv[2]=(_Float16)acc[2]; hv[3]=(_Float16)acc[3];
        *(f16x4*)(&stag[wave][swz(r16, c * 16 + kgrp * 4)]) = hv;
    }
    {
        int nd = lane >> 2;
        int node2 = node_base + nd;
        #pragma unroll
        for (int i = 0; i < 4; ++i) {
            int f0 = (lane & 3) * 8 + i * 32;
            f16x8 v = *(const f16x8*)(&stag[wave][swz(nd, f0)]);
            if (node2 < N_NODES)
                *(f16x8*)(Z + (size_t)node2 * F + f0) = v;
        }
    }
    {
        #pragma unroll
        for (int kk = 0; kk < 4; ++kk)
            *(f16x8*)(&stag[wave][swz(r16, kk * 32 + kgrp * 8)]) = xf[kk];
        int nd = lane >> 2;
        int node2 = node_base + nd;
        #pragma unroll
        for (int i = 0; i < 4; ++i) {
            int f0 = (lane & 3) * 8 + i * 32;
            f16x8 v = *(const f16x8*)(&stag[wave][swz(nd, f0)]);
            if (node2 < N_NODES)
                *(f16x8*)(XH + (size_t)node2 * F + f0) = v;
        }
    }
    {
        float pu = 0.f, pv = 0.f;
        #pragma unroll
        for (int kk = 0; kk < 4; ++kk) {
            int kb = kgrp * 8 + kk * 32;
            float4 u0 = *(const float4*)(uvws + kb);
            float4 u1 = *(const float4*)(uvws + kb + 4);
            float4 v0 = *(const float4*)(uvws + 128 + kb);
            float4 v1 = *(const float4*)(uvws + 128 + kb + 4);
            pu += u0.x*(float)xf[kk][0] + u0.y*(float)xf[kk][1]
                + u0.z*(float)xf[kk][2] + u0.w*(float)xf[kk][3]
                + u1.x*(float)xf[kk][4] + u1.y*(float)xf[kk][5]
                + u1.z*(float)xf[kk][6] + u1.w*(float)xf[kk][7];
            pv += v0.x*(float)xf[kk][0] + v0.y*(float)xf[kk][1]
                + v0.z*(float)xf[kk][2] + v0.w*(float)xf[kk][3]
                + v1.x*(float)xf[kk][4] + v1.y*(float)xf[kk][5]
                + v1.z*(float)xf[kk][6] + v1.w*(float)xf[kk][7];
        }
        pu += __shfl_xor(pu, 16); pu += __shfl_xor(pu, 32);
        pv += __shfl_xor(pv, 16); pv += __shfl_xor(pv, 32);
        if (kgrp == 0 && node < N_NODES) {
            su[node] = pu + uvws[256];
            sv[node] = pv;
        }
    }
}

// ---------------- Edge: sorted (rgrp, cblk), XCD-chunked, 4 lanes/edge ----
__global__ __launch_bounds__(256) void gat_edge(
    const uint2* __restrict__ sorted,
    const _Float16* __restrict__ XH, const _Float16* __restrict__ Z,
    const float* __restrict__ su, const float* __restrict__ sv,
    float* __restrict__ out)
{
    const int nwg = gridDim.x;
    int bid = blockIdx.x;
    int xcd = bid & 7, loc = bid >> 3;
    int q = nwg >> 3, rr = nwg & 7;
    int wg = (xcd < rr ? xcd * (q + 1) : rr * (q + 1) + (xcd - rr) * q) + loc;

    int idx = wg * 64 + (threadIdx.x >> 2);
    int hl  = threadIdx.x & 3;
    if (idx >= N_EDGES) return;

    uint2 rc = sorted[idx];
    int r = rc.x & 0xFFFF;
    int c = rc.x >> 16;

    const _Float16* hp = XH + (size_t)r * F + hl * 32;
    const _Float16* ap = Z  + (size_t)c * F + hl * 32;
    v8v2 a[4], b[4];
    #pragma unroll
    for (int i = 0; i < 4; ++i) a[i].v8 = *(const f16x8*)(hp + i * 8);
    #pragma unroll
    for (int i = 0; i < 4; ++i) b[i].v8 = *(const f16x8*)(ap + i * 8);

    float p = 0.f;
    #pragma unroll
    for (int i = 0; i < 4; ++i)
        #pragma unroll
        for (int j = 0; j < 4; ++j)
            p = __builtin_amdgcn_fdot2(a[i].v2[j], b[i].v2[j], p, false);

    p += __shfl_xor(p, 1);
    p += __shfl_xor(p, 2);

    if (hl == 0) {
        float s = p + su[c] + sv[r];
        out[rc.y] = 1.f / (1.f + __expf(-0.5f * s));
    }
}

extern "C" void kernel_launch(void* const* d_in, const int* in_sizes, int n_in,
                              void* d_out, int out_size, void* d_ws, size_t ws_size,
                              hipStream_t stream) {
    const float* x     = (const float*)d_in[0];
    const int*   ei    = (const int*)d_in[1];
    const float* W_lin = (const float*)d_in[2];
    const float* b_lin = (const float*)d_in[3];
    const float* W_att = (const float*)d_in[4];
    float* out = (float*)d_out;

    // ws: Mall | uvws | XH | Z | su | sv | bcnt | bof | btot | bbase | sorted
    _Float16* Mall  = (_Float16*)d_ws;                       // 32 KB
    float*    uvws  = (float*)(Mall + F * F);                // 512 f32
    _Float16* XH    = (_Float16*)(uvws + 512);               // 12.8 MB
    _Float16* Z     = XH + (size_t)N_NODES * F;              // 12.8 MB
    float*    su    = (float*)(Z + (size_t)N_NODES * F);     // 200 KB
    float*    sv    = su + N_NODES;                          // 200 KB
    unsigned* bcnt  = (unsigned*)(sv + N_NODES);             // 6.4 MB
    unsigned* bof   = bcnt + (size_t)NBUK2 * NBLKP;          // 6.4 MB
    unsigned* btot  = bof + (size_t)NBUK2 * NBLKP;           // 16 KB
    unsigned* bbase = btot + NBUK2;                          // 16 KB
    uint2*    sorted= (uint2*)(bbase + NBUK2);               // 3.2 MB

    gat_fuse<<<16, 256, 0, stream>>>(W_lin, b_lin, W_att, Mall, uvws);
    gat_hist<<<NBLK, 256, 0, stream>>>(ei, bcnt);
    gat_scan_row<<<NBUK2, 512, 0, stream>>>(bcnt, bof, btot);
    gat_scan_bkt<<<1, 512, 0, stream>>>(btot, bbase);
    gat_scatter<<<NBLK, 256, 0, stream>>>(ei, bof, bbase, sorted);

    gat_gemm<<<(N_NODES + 63) / 64, 256, 0, stream>>>(x, Mall, uvws, XH, Z, su, sv);
    gat_edge<<<(N_EDGES + 63) / 64, 256, 0, stream>>>(sorted, XH, Z, su, sv, out);
}

// Round 14
// 83.206 us; speedup vs baseline: 1.3410x; 1.3410x over previous
//
#include <hip/hip_runtime.h>
#include <hip/hip_fp16.h>

constexpr int N_NODES = 50000;
constexpr int N_EDGES = 400000;
constexpr int F = 128;

constexpr int NBUK  = 512;                       // row>>7 buckets (391 used)
constexpr int EPB   = 1024;                      // edges per hist/scatter block
constexpr int NBLK  = (N_EDGES + EPB - 1) / EPB; // 391
constexpr int NBLKP = 392;                       // padded stride [bucket][block]

typedef _Float16 f16x8 __attribute__((ext_vector_type(8)));
typedef _Float16 f16x4 __attribute__((ext_vector_type(4)));
typedef _Float16 f16x2 __attribute__((ext_vector_type(2)));
typedef float    f32x4 __attribute__((ext_vector_type(4)));

union v8v2 { f16x8 v8; f16x2 v2[4]; };

// XOR swizzle: flips half-index bits 3..5 by row&7 -> conflict-free frag reads.
__device__ __forceinline__ int swz(int row, int colh) {
    return (row * F + colh) ^ ((row & 7) << 3);
}

// =============== Algebra: score(e) = x_r^T M x_c + v.x_r + u.x_c + c0 =====
//   M = sum_h W_l^T W_a W_l (f16); u = sum_h W_l^T W_a^T b; v = sum_h W_l^T W_a b
//   c0 = sum_h b^T W_a b
__global__ __launch_bounds__(256) void gat_fuse(
    const float* __restrict__ W_lin, const float* __restrict__ b_lin,
    const float* __restrict__ W_att,
    _Float16* __restrict__ Mall, float* __restrict__ uvws)
{
    __shared__ float wlh[F * F];     // 64 KB
    __shared__ float wfs[F][8];
    __shared__ float bl[F];
    __shared__ float w12[2 * F];
    __shared__ float red[256];

    const int cb = blockIdx.x;
    const int t  = threadIdx.x;
    const int i  = t >> 1, j2 = (t & 1) * 4;
    const int ii = t & 127;

    float acc0 = 0, acc1 = 0, acc2 = 0, acc3 = 0;
    float puv = 0;
    float c0s = 0;

    for (int h = 0; h < 2; ++h) {
        __syncthreads();
        const float* WL = W_lin + h * F * F;
        const float* WA = W_att + h * F * F;
        #pragma unroll
        for (int q = 0; q < 16; ++q) {
            int idx = (q * 256 + t) * 4;
            *(float4*)(wlh + idx) = *(const float4*)(WL + idx);
        }
        if (t < F) bl[t] = b_lin[h * F + t];
        __syncthreads();

        {   int o = t >> 1, jb = (t & 1) * 4;
            float a0=0, a1=0, a2=0, a3=0;
            const float* war = WA + o * F;
            #pragma unroll 4
            for (int p = 0; p < F; ++p) {
                float wa = war[p];
                const float* wr = wlh + p * F + cb * 8 + jb;
                a0 += wa * wr[0]; a1 += wa * wr[1];
                a2 += wa * wr[2]; a3 += wa * wr[3];
            }
            wfs[o][jb+0]=a0; wfs[o][jb+1]=a1; wfs[o][jb+2]=a2; wfs[o][jb+3]=a3;
        }
        if (cb == 0) {
            if (t < F) {
                float s = 0;
                #pragma unroll 4
                for (int o = 0; o < F; ++o) s += WA[o * F + t] * bl[o];
                w12[t] = s;
            } else {
                int o = t - F;
                float s = 0;
                const float* war = WA + o * F;
                #pragma unroll 4
                for (int p = 0; p < F; ++p) s += war[p] * bl[p];
                w12[F + o] = s;
            }
        }
        __syncthreads();

        #pragma unroll 4
        for (int o = 0; o < F; ++o) {
            float wv = wlh[o * F + i];
            acc0 += wv * wfs[o][j2+0];
            acc1 += wv * wfs[o][j2+1];
            acc2 += wv * wfs[o][j2+2];
            acc3 += wv * wfs[o][j2+3];
        }
        if (cb == 0) {
            const float* wsrc = (t < F) ? w12 : (w12 + F);
            #pragma unroll 4
            for (int o = 0; o < F; ++o) puv += wlh[o * F + ii] * wsrc[o];
            red[t] = (t < F) ? bl[t] * w12[F + t] : 0.f;
            __syncthreads();
            #pragma unroll
            for (int d = 128; d > 0; d >>= 1) {
                if (t < d) red[t] += red[t + d];
                __syncthreads();
            }
            if (t == 0) c0s += red[0];
        }
    }

    f16x4 hv;
    hv[0]=(_Float16)acc0; hv[1]=(_Float16)acc1;
    hv[2]=(_Float16)acc2; hv[3]=(_Float16)acc3;
    *(f16x4*)(Mall + i * F + cb * 8 + j2) = hv;

    if (cb == 0) {
        uvws[(t < F ? 0 : F) + ii] = puv;
        if (t == 0) uvws[256] = c0s;
    }
}

// ---------------- Lean deterministic counting sort by row>>7 (R10) --------
__global__ __launch_bounds__(256) void gat_hist(
    const int* __restrict__ ei, unsigned* __restrict__ bcnt)
{
    __shared__ unsigned h[NBUK];
    const int t = threadIdx.x, b = blockIdx.x;
    h[t] = 0; h[t + 256] = 0;
    __syncthreads();
    const int base = b * EPB;
    #pragma unroll
    for (int i = 0; i < EPB / 256; ++i) {
        int e = base + i * 256 + t;
        if (e < N_EDGES) atomicAdd(&h[(unsigned)ei[e] >> 7], 1u);
    }
    __syncthreads();
    bcnt[t * NBLKP + b]         = h[t];
    bcnt[(t + 256) * NBLKP + b] = h[t + 256];
}

__global__ __launch_bounds__(512) void gat_scan_row(
    const unsigned* __restrict__ bcnt, unsigned* __restrict__ bof,
    unsigned* __restrict__ btot)
{
    __shared__ unsigned s[512];
    const int B = blockIdx.x, t = threadIdx.x;
    unsigned v = (t < NBLK) ? bcnt[B * NBLKP + t] : 0u;
    s[t] = v;
    __syncthreads();
    #pragma unroll
    for (int d = 1; d < 512; d <<= 1) {
        unsigned u = (t >= d) ? s[t - d] : 0u;
        __syncthreads();
        s[t] += u;
        __syncthreads();
    }
    if (t < NBLK) bof[B * NBLKP + t] = s[t] - v;
    if (t == 511) btot[B] = s[511];
}

__global__ __launch_bounds__(512) void gat_scan_bkt(
    const unsigned* __restrict__ btot, unsigned* __restrict__ bbase)
{
    __shared__ unsigned s[NBUK];
    const int t = threadIdx.x;
    unsigned v = btot[t];
    s[t] = v;
    __syncthreads();
    #pragma unroll
    for (int d = 1; d < NBUK; d <<= 1) {
        unsigned u = (t >= d) ? s[t - d] : 0u;
        __syncthreads();
        s[t] += u;
        __syncthreads();
    }
    bbase[t] = s[t] - v;
}

__global__ __launch_bounds__(256) void gat_scatter(
    const int* __restrict__ ei, const unsigned* __restrict__ bof,
    const unsigned* __restrict__ bbase, uint2* __restrict__ sorted)
{
    __shared__ unsigned base[NBUK];
    const int t = threadIdx.x, b = blockIdx.x;
    base[t]       = bof[t * NBLKP + b] + bbase[t];
    base[t + 256] = bof[(t + 256) * NBLKP + b] + bbase[t + 256];
    __syncthreads();
    const int bs = b * EPB;
    #pragma unroll
    for (int i = 0; i < EPB / 256; ++i) {
        int e = bs + i * 256 + t;
        if (e < N_EDGES) {
            unsigned r = (unsigned)ei[e], c = (unsigned)ei[N_EDGES + e];
            unsigned pos = atomicAdd(&base[r >> 7], 1u);
            sorted[pos] = make_uint2(r | (c << 16), (unsigned)e);
        }
    }
}

// ---------------- GEMM: Z = x @ M^T, XH = f16(x), su/sv epilogue ----------
__global__ __launch_bounds__(256) void gat_gemm(
    const float* __restrict__ x,
    const _Float16* __restrict__ Mall,
    const float* __restrict__ uvws,
    _Float16* __restrict__ XH, _Float16* __restrict__ Z,
    float* __restrict__ su, float* __restrict__ sv)
{
    __shared__ _Float16 wbuf[F * F];
    __shared__ _Float16 stag[4][16 * F];

    const int t    = threadIdx.x;
    const int wave = t >> 6;
    const int lane = t & 63;
    const int r16  = lane & 15;
    const int kgrp = lane >> 4;
    const int node_base = blockIdx.x * 64 + wave * 16;

    #pragma unroll
    for (int i = 0; i < 8; ++i) {
        int idx8 = i * 256 + t;
        *(f16x8*)(wbuf + swz(idx8 >> 4, (idx8 & 15) * 8)) =
            *(const f16x8*)(Mall + (size_t)idx8 * 8);
    }

    f16x8 xf[4];
    {
        int xrow = node_base + r16;
        if (xrow >= N_NODES) xrow = N_NODES - 1;
        const float* xp = x + (size_t)xrow * F + kgrp * 8;
        #pragma unroll
        for (int kk = 0; kk < 4; ++kk) {
            float4 v0 = *(const float4*)(xp + kk * 32);
            float4 v1 = *(const float4*)(xp + kk * 32 + 4);
            f16x8 hv;
            hv[0]=(_Float16)v0.x; hv[1]=(_Float16)v0.y;
            hv[2]=(_Float16)v0.z; hv[3]=(_Float16)v0.w;
            hv[4]=(_Float16)v1.x; hv[5]=(_Float16)v1.y;
            hv[6]=(_Float16)v1.z; hv[7]=(_Float16)v1.w;
            xf[kk] = hv;
        }
    }
    __syncthreads();

    const int node = node_base + r16;

    #pragma unroll
    for (int c = 0; c < 8; ++c) {
        f16x8 aw[4];
        #pragma unroll
        for (int kk = 0; kk < 4; ++kk)
            aw[kk] = *(const f16x8*)(wbuf + swz(c * 16 + r16, kk * 32 + kgrp * 8));
        f32x4 acc = {0.f, 0.f, 0.f, 0.f};
        #pragma unroll
        for (int kk = 0; kk < 4; ++kk)
            acc = __builtin_amdgcn_mfma_f32_16x16x32_f16(aw[kk], xf[kk], acc, 0, 0, 0);
        f16x4 hv;
        hv[0]=(_Float16)acc[0]; hv[1]=(_Float16)acc[1];
        hv[2]=(_Float16)acc[2]; hv[3]=(_Float16)acc[3];
        *(f16x4*)(&stag[wave][swz(r16, c * 16 + kgrp * 4)]) = hv;
    }
    {
        int nd = lane >> 2;
        int node2 = node_base + nd;
        #pragma unroll
        for (int i = 0; i < 4; ++i) {
            int f0 = (lane & 3) * 8 + i * 32;
            f16x8 v = *(const f16x8*)(&stag[wave][swz(nd, f0)]);
            if (node2 < N_NODES)
                *(f16x8*)(Z + (size_t)node2 * F + f0) = v;
        }
    }
    {
        #pragma unroll
        for (int kk = 0; kk < 4; ++kk)
            *(f16x8*)(&stag[wave][swz(r16, kk * 32 + kgrp * 8)]) = xf[kk];
        int nd = lane >> 2;
        int node2 = node_base + nd;
        #pragma unroll
        for (int i = 0; i < 4; ++i) {
            int f0 = (lane & 3) * 8 + i * 32;
            f16x8 v = *(const f16x8*)(&stag[wave][swz(nd, f0)]);
            if (node2 < N_NODES)
                *(f16x8*)(XH + (size_t)node2 * F + f0) = v;
        }
    }
    {
        float pu = 0.f, pv = 0.f;
        #pragma unroll
        for (int kk = 0; kk < 4; ++kk) {
            int kb = kgrp * 8 + kk * 32;
            float4 u0 = *(const float4*)(uvws + kb);
            float4 u1 = *(const float4*)(uvws + kb + 4);
            float4 v0 = *(const float4*)(uvws + 128 + kb);
            float4 v1 = *(const float4*)(uvws + 128 + kb + 4);
            pu += u0.x*(float)xf[kk][0] + u0.y*(float)xf[kk][1]
                + u0.z*(float)xf[kk][2] + u0.w*(float)xf[kk][3]
                + u1.x*(float)xf[kk][4] + u1.y*(float)xf[kk][5]
                + u1.z*(float)xf[kk][6] + u1.w*(float)xf[kk][7];
            pv += v0.x*(float)xf[kk][0] + v0.y*(float)xf[kk][1]
                + v0.z*(float)xf[kk][2] + v0.w*(float)xf[kk][3]
                + v1.x*(float)xf[kk][4] + v1.y*(float)xf[kk][5]
                + v1.z*(float)xf[kk][6] + v1.w*(float)xf[kk][7];
        }
        pu += __shfl_xor(pu, 16); pu += __shfl_xor(pu, 32);
        pv += __shfl_xor(pv, 16); pv += __shfl_xor(pv, 32);
        if (kgrp == 0 && node < N_NODES) {
            su[node] = pu + uvws[256];
            sv[node] = pv;
        }
    }
}

// ---------------- Edge: row-sorted + XCD-chunked, 4 lanes/edge ------------
__global__ __launch_bounds__(256) void gat_edge(
    const uint2* __restrict__ sorted,
    const _Float16* __restrict__ XH, const _Float16* __restrict__ Z,
    const float* __restrict__ su, const float* __restrict__ sv,
    float* __restrict__ out)
{
    const int nwg = gridDim.x;
    int bid = blockIdx.x;
    int xcd = bid & 7, loc = bid >> 3;
    int q = nwg >> 3, rr = nwg & 7;
    int wg = (xcd < rr ? xcd * (q + 1) : rr * (q + 1) + (xcd - rr) * q) + loc;

    int idx = wg * 64 + (threadIdx.x >> 2);
    int hl  = threadIdx.x & 3;
    if (idx >= N_EDGES) return;

    uint2 rc = sorted[idx];
    int r = rc.x & 0xFFFF;
    int c = rc.x >> 16;

    const _Float16* hp = XH + (size_t)r * F + hl * 32;
    const _Float16* ap = Z  + (size_t)c * F + hl * 32;
    v8v2 a[4], b[4];
    #pragma unroll
    for (int i = 0; i < 4; ++i) a[i].v8 = *(const f16x8*)(hp + i * 8);
    #pragma unroll
    for (int i = 0; i < 4; ++i) b[i].v8 = *(const f16x8*)(ap + i * 8);

    float p = 0.f;
    #pragma unroll
    for (int i = 0; i < 4; ++i)
        #pragma unroll
        for (int j = 0; j < 4; ++j)
            p = __builtin_amdgcn_fdot2(a[i].v2[j], b[i].v2[j], p, false);

    p += __shfl_xor(p, 1);
    p += __shfl_xor(p, 2);

    if (hl == 0) {
        float s = p + su[c] + sv[r];
        out[rc.y] = 1.f / (1.f + __expf(-0.5f * s));
    }
}

extern "C" void kernel_launch(void* const* d_in, const int* in_sizes, int n_in,
                              void* d_out, int out_size, void* d_ws, size_t ws_size,
                              hipStream_t stream) {
    const float* x     = (const float*)d_in[0];
    const int*   ei    = (const int*)d_in[1];
    const float* W_lin = (const float*)d_in[2];
    const float* b_lin = (const float*)d_in[3];
    const float* W_att = (const float*)d_in[4];
    float* out = (float*)d_out;

    // ws: Mall | uvws | XH | Z | su | sv | bcnt | bof | btot | bbase | sorted
    _Float16* Mall  = (_Float16*)d_ws;                       // 32 KB
    float*    uvws  = (float*)(Mall + F * F);                // 512 f32
    _Float16* XH    = (_Float16*)(uvws + 512);               // 12.8 MB
    _Float16* Z     = XH + (size_t)N_NODES * F;              // 12.8 MB
    float*    su    = (float*)(Z + (size_t)N_NODES * F);     // 200 KB
    float*    sv    = su + N_NODES;                          // 200 KB
    unsigned* bcnt  = (unsigned*)(sv + N_NODES);             // 800 KB
    unsigned* bof   = bcnt + NBUK * NBLKP;                   // 800 KB
    unsigned* btot  = bof + NBUK * NBLKP;                    // 2 KB
    unsigned* bbase = btot + NBUK;                           // 2 KB
    uint2*    sorted= (uint2*)(bbase + NBUK);                // 3.2 MB

    gat_fuse<<<16, 256, 0, stream>>>(W_lin, b_lin, W_att, Mall, uvws);
    gat_hist<<<NBLK, 256, 0, stream>>>(ei, bcnt);
    gat_scan_row<<<NBUK, 512, 0, stream>>>(bcnt, bof, btot);
    gat_scan_bkt<<<1, NBUK, 0, stream>>>(btot, bbase);
    gat_scatter<<<NBLK, 256, 0, stream>>>(ei, bof, bbase, sorted);

    gat_gemm<<<(N_NODES + 63) / 64, 256, 0, stream>>>(x, Mall, uvws, XH, Z, su, sv);
    gat_edge<<<(N_EDGES + 63) / 64, 256, 0, stream>>>(sorted, XH, Z, su, sv, out);
}

// Round 15
// 73.149 us; speedup vs baseline: 1.5253x; 1.1375x over previous
//
#include <hip/hip_runtime.h>
#include <hip/hip_fp16.h>

constexpr int N_NODES = 50000;
constexpr int N_EDGES = 400000;
constexpr int F = 128;

typedef _Float16 f16x8 __attribute__((ext_vector_type(8)));
typedef _Float16 f16x4 __attribute__((ext_vector_type(4)));
typedef _Float16 f16x2 __attribute__((ext_vector_type(2)));
typedef float    f32x4 __attribute__((ext_vector_type(4)));

union v8v2 { f16x8 v8; f16x2 v2[4]; };

// XOR swizzle: flips half-index bits 3..5 by row&7 -> conflict-free frag reads.
__device__ __forceinline__ int swz(int row, int colh) {
    return (row * F + colh) ^ ((row & 7) << 3);
}

// =============== Algebra: score(e) = x_r^T M x_c + v.x_r + u.x_c + c0 =====
//   M = sum_h W_l^T W_a W_l (f16); u = sum_h W_l^T W_a^T b; v = sum_h W_l^T W_a b
//   c0 = sum_h b^T W_a b
__global__ __launch_bounds__(256) void gat_fuse(
    const float* __restrict__ W_lin, const float* __restrict__ b_lin,
    const float* __restrict__ W_att,
    _Float16* __restrict__ Mall, float* __restrict__ uvws)
{
    __shared__ float wlh[F * F];     // 64 KB
    __shared__ float wfs[F][8];
    __shared__ float bl[F];
    __shared__ float w12[2 * F];
    __shared__ float red[256];

    const int cb = blockIdx.x;
    const int t  = threadIdx.x;
    const int i  = t >> 1, j2 = (t & 1) * 4;
    const int ii = t & 127;

    float acc0 = 0, acc1 = 0, acc2 = 0, acc3 = 0;
    float puv = 0;
    float c0s = 0;

    for (int h = 0; h < 2; ++h) {
        __syncthreads();
        const float* WL = W_lin + h * F * F;
        const float* WA = W_att + h * F * F;
        #pragma unroll
        for (int q = 0; q < 16; ++q) {
            int idx = (q * 256 + t) * 4;
            *(float4*)(wlh + idx) = *(const float4*)(WL + idx);
        }
        if (t < F) bl[t] = b_lin[h * F + t];
        __syncthreads();

        {   int o = t >> 1, jb = (t & 1) * 4;
            float a0=0, a1=0, a2=0, a3=0;
            const float* war = WA + o * F;
            #pragma unroll 4
            for (int p = 0; p < F; ++p) {
                float wa = war[p];
                const float* wr = wlh + p * F + cb * 8 + jb;
                a0 += wa * wr[0]; a1 += wa * wr[1];
                a2 += wa * wr[2]; a3 += wa * wr[3];
            }
            wfs[o][jb+0]=a0; wfs[o][jb+1]=a1; wfs[o][jb+2]=a2; wfs[o][jb+3]=a3;
        }
        if (cb == 0) {
            if (t < F) {
                float s = 0;
                #pragma unroll 4
                for (int o = 0; o < F; ++o) s += WA[o * F + t] * bl[o];
                w12[t] = s;
            } else {
                int o = t - F;
                float s = 0;
                const float* war = WA + o * F;
                #pragma unroll 4
                for (int p = 0; p < F; ++p) s += war[p] * bl[p];
                w12[F + o] = s;
            }
        }
        __syncthreads();

        #pragma unroll 4
        for (int o = 0; o < F; ++o) {
            float wv = wlh[o * F + i];
            acc0 += wv * wfs[o][j2+0];
            acc1 += wv * wfs[o][j2+1];
            acc2 += wv * wfs[o][j2+2];
            acc3 += wv * wfs[o][j2+3];
        }
        if (cb == 0) {
            const float* wsrc = (t < F) ? w12 : (w12 + F);
            #pragma unroll 4
            for (int o = 0; o < F; ++o) puv += wlh[o * F + ii] * wsrc[o];
            red[t] = (t < F) ? bl[t] * w12[F + t] : 0.f;
            __syncthreads();
            #pragma unroll
            for (int d = 128; d > 0; d >>= 1) {
                if (t < d) red[t] += red[t + d];
                __syncthreads();
            }
            if (t == 0) c0s += red[0];
        }
    }

    f16x4 hv;
    hv[0]=(_Float16)acc0; hv[1]=(_Float16)acc1;
    hv[2]=(_Float16)acc2; hv[3]=(_Float16)acc3;
    *(f16x4*)(Mall + i * F + cb * 8 + j2) = hv;

    if (cb == 0) {
        uvws[(t < F ? 0 : F) + ii] = puv;
        if (t == 0) uvws[256] = c0s;
    }
}

// ---------------- GEMM: Z = x @ M^T, XH = f16(x) direct, su/sv epilogue ---
__global__ __launch_bounds__(256) void gat_gemm(
    const float* __restrict__ x,
    const _Float16* __restrict__ Mall,
    const float* __restrict__ uvws,
    _Float16* __restrict__ XH, _Float16* __restrict__ Z,
    float* __restrict__ su, float* __restrict__ sv)
{
    __shared__ _Float16 wbuf[F * F];       // 32 KB
    __shared__ _Float16 stag[4][16 * F];   // 16 KB (Z transpose only)

    const int t    = threadIdx.x;
    const int wave = t >> 6;
    const int lane = t & 63;
    const int r16  = lane & 15;
    const int kgrp = lane >> 4;
    const int node_base = blockIdx.x * 64 + wave * 16;

    #pragma unroll
    for (int i = 0; i < 8; ++i) {
        int idx8 = i * 256 + t;
        *(f16x8*)(wbuf + swz(idx8 >> 4, (idx8 & 15) * 8)) =
            *(const f16x8*)(Mall + (size_t)idx8 * 8);
    }

    f16x8 xf[4];
    {
        int xrow = node_base + r16;
        if (xrow >= N_NODES) xrow = N_NODES - 1;
        const float* xp = x + (size_t)xrow * F + kgrp * 8;
        #pragma unroll
        for (int kk = 0; kk < 4; ++kk) {
            float4 v0 = *(const float4*)(xp + kk * 32);
            float4 v1 = *(const float4*)(xp + kk * 32 + 4);
            f16x8 hv;
            hv[0]=(_Float16)v0.x; hv[1]=(_Float16)v0.y;
            hv[2]=(_Float16)v0.z; hv[3]=(_Float16)v0.w;
            hv[4]=(_Float16)v1.x; hv[5]=(_Float16)v1.y;
            hv[6]=(_Float16)v1.z; hv[7]=(_Float16)v1.w;
            xf[kk] = hv;
        }
    }
    __syncthreads();

    const int node = node_base + r16;
    const bool ok  = node < N_NODES;

    // XH = f16(x): direct 16B stores; lanes kgrp0..3 of a row form 64B segs
    if (ok) {
        #pragma unroll
        for (int kk = 0; kk < 4; ++kk)
            *(f16x8*)(XH + (size_t)node * F + kgrp * 8 + kk * 32) = xf[kk];
    }

    // Z = M @ x (D-frag col = node, rows = features) via stag transpose
    #pragma unroll
    for (int c = 0; c < 8; ++c) {
        f16x8 aw[4];
        #pragma unroll
        for (int kk = 0; kk < 4; ++kk)
            aw[kk] = *(const f16x8*)(wbuf + swz(c * 16 + r16, kk * 32 + kgrp * 8));
        f32x4 acc = {0.f, 0.f, 0.f, 0.f};
        #pragma unroll
        for (int kk = 0; kk < 4; ++kk)
            acc = __builtin_amdgcn_mfma_f32_16x16x32_f16(aw[kk], xf[kk], acc, 0, 0, 0);
        f16x4 hv;
        hv[0]=(_Float16)acc[0]; hv[1]=(_Float16)acc[1];
        hv[2]=(_Float16)acc[2]; hv[3]=(_Float16)acc[3];
        *(f16x4*)(&stag[wave][swz(r16, c * 16 + kgrp * 4)]) = hv;
    }
    {
        int nd = lane >> 2;
        int node2 = node_base + nd;
        #pragma unroll
        for (int i = 0; i < 4; ++i) {
            int f0 = (lane & 3) * 8 + i * 32;
            f16x8 v = *(const f16x8*)(&stag[wave][swz(nd, f0)]);
            if (node2 < N_NODES)
                *(f16x8*)(Z + (size_t)node2 * F + f0) = v;
        }
    }
    {
        float pu = 0.f, pv = 0.f;
        #pragma unroll
        for (int kk = 0; kk < 4; ++kk) {
            int kb = kgrp * 8 + kk * 32;
            float4 u0 = *(const float4*)(uvws + kb);
            float4 u1 = *(const float4*)(uvws + kb + 4);
            float4 v0 = *(const float4*)(uvws + 128 + kb);
            float4 v1 = *(const float4*)(uvws + 128 + kb + 4);
            pu += u0.x*(float)xf[kk][0] + u0.y*(float)xf[kk][1]
                + u0.z*(float)xf[kk][2] + u0.w*(float)xf[kk][3]
                + u1.x*(float)xf[kk][4] + u1.y*(float)xf[kk][5]
                + u1.z*(float)xf[kk][6] + u1.w*(float)xf[kk][7];
            pv += v0.x*(float)xf[kk][0] + v0.y*(float)xf[kk][1]
                + v0.z*(float)xf[kk][2] + v0.w*(float)xf[kk][3]
                + v1.x*(float)xf[kk][4] + v1.y*(float)xf[kk][5]
                + v1.z*(float)xf[kk][6] + v1.w*(float)xf[kk][7];
        }
        pu += __shfl_xor(pu, 16); pu += __shfl_xor(pu, 32);
        pv += __shfl_xor(pv, 16); pv += __shfl_xor(pv, 32);
        if (kgrp == 0 && ok) {
            su[node] = pu + uvws[256];
            sv[node] = pv;
        }
    }
}

// ---------------- Edge: unsorted, 16 edges/wave, 4 lanes/edge -------------
// score = dot(XH[r], Z[c]) + su[c] + sv[r]; out = sigmoid(score/2).
__global__ __launch_bounds__(256) void gat_edge(
    const int* __restrict__ ei,          // [2][N_EDGES]
    const _Float16* __restrict__ XH, const _Float16* __restrict__ Z,
    const float* __restrict__ su, const float* __restrict__ sv,
    float* __restrict__ out)
{
    int gid = blockIdx.x * 256 + threadIdx.x;
    int e   = gid >> 2;
    int hl  = threadIdx.x & 3;
    if (e >= N_EDGES) return;

    int r = ei[e];
    int c = ei[N_EDGES + e];

    const _Float16* hp = XH + (size_t)r * F + hl * 32;
    const _Float16* ap = Z  + (size_t)c * F + hl * 32;
    v8v2 a[4], b[4];
    #pragma unroll
    for (int i = 0; i < 4; ++i) a[i].v8 = *(const f16x8*)(hp + i * 8);
    #pragma unroll
    for (int i = 0; i < 4; ++i) b[i].v8 = *(const f16x8*)(ap + i * 8);

    float p = 0.f;
    #pragma unroll
    for (int i = 0; i < 4; ++i)
        #pragma unroll
        for (int j = 0; j < 4; ++j)
            p = __builtin_amdgcn_fdot2(a[i].v2[j], b[i].v2[j], p, false);

    p += __shfl_xor(p, 1);
    p += __shfl_xor(p, 2);

    if (hl == 0) {
        float s = p + su[c] + sv[r];
        out[e] = 1.f / (1.f + __expf(-0.5f * s));
    }
}

extern "C" void kernel_launch(void* const* d_in, const int* in_sizes, int n_in,
                              void* d_out, int out_size, void* d_ws, size_t ws_size,
                              hipStream_t stream) {
    const float* x     = (const float*)d_in[0];
    const int*   ei    = (const int*)d_in[1];
    const float* W_lin = (const float*)d_in[2];
    const float* b_lin = (const float*)d_in[3];
    const float* W_att = (const float*)d_in[4];
    float* out = (float*)d_out;

    // ws: Mall | uvws | XH | Z | su | sv   (~26 MB)
    _Float16* Mall = (_Float16*)d_ws;                       // 32 KB
    float*    uvws = (float*)(Mall + F * F);                // 512 f32
    _Float16* XH   = (_Float16*)(uvws + 512);               // 12.8 MB
    _Float16* Z    = XH + (size_t)N_NODES * F;              // 12.8 MB
    float*    su   = (float*)(Z + (size_t)N_NODES * F);     // 200 KB
    float*    sv   = su + N_NODES;                          // 200 KB

    gat_fuse<<<16, 256, 0, stream>>>(W_lin, b_lin, W_att, Mall, uvws);
    gat_gemm<<<(N_NODES + 63) / 64, 256, 0, stream>>>(x, Mall, uvws, XH, Z, su, sv);
    gat_edge<<<(N_EDGES * 4 + 255) / 256, 256, 0, stream>>>(ei, XH, Z, su, sv, out);
}